// Round 9
// baseline (1331.349 us; speedup 1.0000x reference)
//
#include <hip/hip_runtime.h>
#include <hip/hip_bf16.h>
#include <math.h>

#define BATCH     256
#define DMODEL    2048
#define DSTATE    128
#define HEADDIM_  64
#define DINNER    4096
#define NHEADS_   64
#define CONVDIM   4352
#define DINPROJ   8512
#define EPS_      1e-5f

// ======== PROBE ROUND: kernels internally repeated to exceed the ~330 µs
// rocprof fill threshold so their counters appear in top-5. Numerics are
// preserved (gemm: accumulate REP x then scale 1/REP; ssm: idempotent).
#define G1REP 24
#define G2REP 32
#define SSMREP 5

typedef __attribute__((ext_vector_type(8))) short short8;
typedef __attribute__((ext_vector_type(4))) short short4v;
typedef __attribute__((ext_vector_type(4))) float f32x4;

__device__ __forceinline__ short bfbits(float f) {
    __hip_bfloat16 h = __float2bfloat16(f);
    return *reinterpret_cast<short*>(&h);
}
__device__ __forceinline__ short8 cvt8(float4 a, float4 b) {
    short8 r;
    r[0] = bfbits(a.x); r[1] = bfbits(a.y); r[2] = bfbits(a.z); r[3] = bfbits(a.w);
    r[4] = bfbits(b.x); r[5] = bfbits(b.y); r[6] = bfbits(b.z); r[7] = bfbits(b.w);
    return r;
}
// XOR-swizzle for [rows][128B] bf16 LDS tiles (same map on write and read).
__device__ __forceinline__ int swz(int row, int cb) {
    return row * 128 + (cb ^ ((row & 7) << 4));
}

// ---------------- f32 -> bf16 pre-convert (hid) ----------------
__global__ __launch_bounds__(256)
void f2b(const float* __restrict__ in, short* __restrict__ o) {
    int i = (blockIdx.x * 256 + threadIdx.x) * 8;
    float4 a = *(const float4*)(in + i);
    float4 b = *(const float4*)(in + i + 4);
    *(short8*)(o + i) = cvt8(a, b);
}

// ---------- bf16 MFMA GEMM (R5 structure + rep): C = (1/rep)*sum_rep A*W^T ----------
template<int TH, int BN>
__global__ __launch_bounds__(TH, 2)
void gemm_mfma(const short* __restrict__ A, const float* __restrict__ W,
               float* __restrict__ C, int lda, int ldb, int ldc, int kc,
               int rep, float oscale) {
    constexpr int WNC = BN / 32;
    constexpr int ASL = 2048 / TH;
    constexpr int BBYTES = BN * 128;
    const int bn0 = blockIdx.x * BN;
    const int k0  = blockIdx.z * kc;
    C += (size_t)blockIdx.z * 256 * ldc;
    const int t = threadIdx.x;
    const int lane = t & 63;
    const int w = t >> 6;
    const int wm = w / WNC, wn = w % WNC;
    const int fr = lane & 15, fg = lane >> 4;

    __shared__ __align__(16) char lds[2][32768 + BBYTES];

    const short* apb[ASL]; int ao[ASL];
    #pragma unroll
    for (int i = 0; i < ASL; ++i) {
        int s = t + TH * i, r = s >> 3, sl = s & 7;
        apb[i] = A + (size_t)r * lda + k0 + sl * 8;
        ao[i] = swz(r, sl * 16);
    }
    const int br = t >> 3, bsl = t & 7;
    const float* bp = W + (size_t)(bn0 + br) * ldb + k0 + bsl * 8;
    const int bo = 32768 + swz(br, bsl * 16);

    int aro[4], bro[2];
    #pragma unroll
    for (int m = 0; m < 4; ++m) aro[m] = swz(wm * 64 + m * 16 + fr, fg * 16);
    #pragma unroll
    for (int n = 0; n < 2; ++n) bro[n] = 32768 + swz(wn * 32 + n * 16 + fr, fg * 16);

    f32x4 acc[4][2] = {};
    short8 rab[ASL];
    float4 rb0, rb1;

    #define LOADT(kt) { const int ko = (kt) << 6;                                \
        _Pragma("unroll") for (int i = 0; i < ASL; ++i)                          \
            rab[i] = *(const short8*)(apb[i] + ko);                              \
        rb0 = *(const float4*)(bp + ko); rb1 = *(const float4*)(bp + ko + 4); }
    #define STAGET(buf) {                                                        \
        _Pragma("unroll") for (int i = 0; i < ASL; ++i)                          \
            *(short8*)(lds[buf] + ao[i]) = rab[i];                               \
        *(short8*)(lds[buf] + bo) = cvt8(rb0, rb1); }

    LOADT(0);
    STAGET(0);
    int cur = 0;
    const int nT = kc >> 6;
    const int total = nT * rep;
    for (int it = 0; it < total; ++it) {
        const int nxt = (it + 1 < total) ? ((it + 1) & (nT - 1)) : -1;
        if (nxt >= 0) LOADT(nxt);
        __syncthreads();
        #pragma unroll
        for (int ks = 0; ks < 2; ++ks) {
            short8 af[4], bf[2];
            #pragma unroll
            for (int m = 0; m < 4; ++m) af[m] = *(short8*)(lds[cur] + (aro[m] ^ (ks << 6)));
            #pragma unroll
            for (int n = 0; n < 2; ++n) bf[n] = *(short8*)(lds[cur] + (bro[n] ^ (ks << 6)));
            #pragma unroll
            for (int m = 0; m < 4; ++m)
                #pragma unroll
                for (int n = 0; n < 2; ++n)
                    acc[m][n] = __builtin_amdgcn_mfma_f32_16x16x32_bf16(af[m], bf[n], acc[m][n], 0, 0, 0);
        }
        if (nxt >= 0) STAGET(cur ^ 1);
        cur ^= 1;
    }
    #pragma unroll
    for (int m = 0; m < 4; ++m)
        #pragma unroll
        for (int n = 0; n < 2; ++n) {
            const int row = wm * 64 + m * 16 + fg * 4;
            const int col = bn0 + wn * 32 + n * 16 + fr;
            #pragma unroll
            for (int j = 0; j < 4; ++j)
                C[(size_t)(row + j) * ldc + col] = acc[m][n][j] * oscale;
        }
    #undef LOADT
    #undef STAGET
}

// sum 4 split-K partials (gemm2)
__global__ __launch_bounds__(256)
void reduce4(const float* __restrict__ part, float* __restrict__ out) {
    const int i = (blockIdx.x * 256 + threadIdx.x) * 4;
    float4 s = *(const float4*)(part + i);
    #pragma unroll
    for (int k = 1; k < 4; ++k) {
        float4 p = *(const float4*)(part + (size_t)k * BATCH * DMODEL + i);
        s.x += p.x; s.y += p.y; s.z += p.z; s.w += p.w;
    }
    *(float4*)(out + i) = s;
}

// ---------- fused middle (R5 structure, phase 3 repeated SSMREP x) ----------
__global__ __launch_bounds__(1024)
void fused_mid(const float* __restrict__ zx, const float* __restrict__ conv_state,
               const float* __restrict__ conv_w, const float* __restrict__ conv_b,
               const float* __restrict__ dt_bias, const float* __restrict__ A_log,
               const float* __restrict__ ssm, const float* __restrict__ Dp,
               const float* __restrict__ nw, short* __restrict__ yn) {
    const int b = blockIdx.x, t = threadIdx.x;
    const int lane = t & 63, w = t >> 6;            // 16 waves
    __shared__ float sxbc[CONVDIM];
    __shared__ float sy[DINNER];
    __shared__ float sred[16];
    __shared__ float sdA[NHEADS_], scoef[NHEADS_];

    // ---- phase 1: conv + silu ----
    #pragma unroll
    for (int it = 0; it < 5; ++it) {
        int c = it * 1024 + t;
        if (c < CONVDIM) {
            float4 cs = *(const float4*)&conv_state[((size_t)b * CONVDIM + c) * 4];
            float4 w4 = *(const float4*)&conv_w[c * 4];
            float xin = zx[(size_t)b * DINPROJ + DINNER + c];
            float v = cs.y * w4.x + cs.z * w4.y + cs.w * w4.z + xin * w4.w + conv_b[c];
            sxbc[c] = v / (1.f + expf(-v));
        }
    }
    __syncthreads();

    // ---- phase 2: BC = B.C ; per-head dt, dA, coef ----
    if (t < 128) {
        float prod = sxbc[DINNER + t] * sxbc[DINNER + DSTATE + t];
        #pragma unroll
        for (int m = 1; m < 64; m <<= 1) prod += __shfl_xor(prod, m);
        if ((t & 63) == 0) sred[t >> 6] = prod;
    }
    __syncthreads();
    if (t < NHEADS_) {
        float BC = sred[0] + sred[1];
        float x = zx[(size_t)b * DINPROJ + DINNER + CONVDIM + t] + dt_bias[t];
        float dt = (x > 20.f) ? x : log1pf(expf(x));
        sdA[t] = expf(dt * (-expf(A_log[t])));
        scoef[t] = dt * BC + Dp[t];
    }
    __syncthreads();

    // ---- phase 3 (repeated SSMREP x, idempotent): SSM contraction ----
    #pragma clang loop unroll(disable)
    for (int r = 0; r < SSMREP; ++r) {
        const int pq = lane >> 4, nl = lane & 15;
        const float4 c4a = *(const float4*)&sxbc[DINNER + DSTATE + nl * 8];
        const float4 c4b = *(const float4*)&sxbc[DINNER + DSTATE + nl * 8 + 4];
        #pragma unroll
        for (int k = 0; k < 4; ++k) {
            const int h = w * 4 + k;
            const float* S = ssm + (((size_t)b * NHEADS_ + h) * HEADDIM_) * DSTATE;
            const float dA = sdA[h], coef = scoef[h];
            #pragma unroll 8
            for (int pp = 0; pp < 16; ++pp) {
                const int p = pp * 4 + pq;
                float4 sa = *(const float4*)&S[p * DSTATE + nl * 8];
                float4 sb = *(const float4*)&S[p * DSTATE + nl * 8 + 4];
                float dot = sa.x * c4a.x + sa.y * c4a.y + sa.z * c4a.z + sa.w * c4a.w
                          + sb.x * c4b.x + sb.y * c4b.y + sb.z * c4b.z + sb.w * c4b.w;
                #pragma unroll
                for (int m = 1; m < 16; m <<= 1) dot += __shfl_xor(dot, m);
                if (nl == 0)
                    sy[h * HEADDIM_ + p] = dA * dot + sxbc[h * HEADDIM_ + p] * coef;
            }
        }
    }
    __syncthreads();

    // ---- phase 4: gate with silu(z), RMSNorm, -> bf16 ----
    {
        const int i = t * 4;
        float4 yv = *(const float4*)&sy[i];
        float4 zv = *(const float4*)&zx[(size_t)b * DINPROJ + i];
        float4 g;
        g.x = yv.x * (zv.x / (1.f + expf(-zv.x)));
        g.y = yv.y * (zv.y / (1.f + expf(-zv.y)));
        g.z = yv.z * (zv.z / (1.f + expf(-zv.z)));
        g.w = yv.w * (zv.w / (1.f + expf(-zv.w)));
        float ss = g.x * g.x + g.y * g.y + g.z * g.z + g.w * g.w;
        #pragma unroll
        for (int m = 1; m < 64; m <<= 1) ss += __shfl_xor(ss, m);
        __syncthreads();
        if (lane == 0) sred[w] = ss;
        __syncthreads();
        float tot = 0.f;
        #pragma unroll
        for (int k = 0; k < 16; ++k) tot += sred[k];
        const float sc = rsqrtf(tot * (1.f / DINNER) + EPS_);
        float4 w4 = *(const float4*)&nw[i];
        short4v o;
        o[0] = bfbits(g.x * sc * w4.x); o[1] = bfbits(g.y * sc * w4.y);
        o[2] = bfbits(g.z * sc * w4.z); o[3] = bfbits(g.w * sc * w4.w);
        *(short4v*)&yn[(size_t)b * DINNER + i] = o;
    }
}

extern "C" void kernel_launch(void* const* d_in, const int* in_sizes, int n_in,
                              void* d_out, int out_size, void* d_ws, size_t ws_size,
                              hipStream_t stream) {
    const float* hid        = (const float*)d_in[0];
    const float* conv_state = (const float*)d_in[1];
    const float* ssm        = (const float*)d_in[2];
    const float* W_in       = (const float*)d_in[3];
    const float* conv_w     = (const float*)d_in[4];
    const float* conv_b     = (const float*)d_in[5];
    const float* dt_bias    = (const float*)d_in[6];
    const float* A_log      = (const float*)d_in[7];
    const float* Dp         = (const float*)d_in[8];
    const float* norm_w     = (const float*)d_in[9];
    const float* W_out      = (const float*)d_in[10];
    float* out = (float*)d_out;

    float* ws    = (float*)d_ws;
    float* zx    = ws;                                  // 256*8512 f32
    float* part  = zx + (size_t)BATCH * DINPROJ;        // 4*256*2048 f32
    short* hidbf = (short*)(part + (size_t)4 * BATCH * DMODEL);  // 256*2048 bf16
    short* yn_bf = hidbf + (size_t)BATCH * DMODEL;      // 256*4096 bf16

    // 0) hid -> bf16
    f2b<<<dim3(BATCH * DMODEL / 2048), 256, 0, stream>>>(hid, hidbf);
    // 1) zxbcdt = h @ W_in^T  (probe: x24 internal repeat)
    gemm_mfma<512, 64><<<dim3(DINPROJ / 64, 1, 1), 512, 0, stream>>>(
        hidbf, W_in, zx, DMODEL, DMODEL, DINPROJ, DMODEL, G1REP, 1.0f / G1REP);
    // 2) fused conv/scalars/SSM/gate-norm (probe: phase-3 x5)
    fused_mid<<<dim3(BATCH), 1024, 0, stream>>>(
        zx, conv_state, conv_w, conv_b, dt_bias, A_log, ssm, Dp, norm_w, yn_bf);
    // 3) out = yn @ W_out^T  split-K x4 (probe: x32 internal repeat)
    gemm_mfma<256, 32><<<dim3(DMODEL / 32, 1, 4), 256, 0, stream>>>(
        yn_bf, W_out, part, DINNER, DINNER, DMODEL, DINNER / 4, G2REP, 1.0f / G2REP);
    reduce4<<<dim3(BATCH * DMODEL / 1024), 256, 0, stream>>>(part, out);
}

// Round 11
// 148.443 us; speedup vs baseline: 8.9688x; 8.9688x over previous
//
#include <hip/hip_runtime.h>
#include <hip/hip_bf16.h>
#include <math.h>

#define BATCH     256
#define DMODEL    2048
#define DSTATE    128
#define HEADDIM_  64
#define DINNER    4096
#define NHEADS_   64
#define CONVDIM   4352
#define DINPROJ   8512
#define EPS_      1e-5f

typedef __attribute__((ext_vector_type(8))) short short8;
typedef __attribute__((ext_vector_type(4))) short short4v;
typedef __attribute__((ext_vector_type(4))) float f32x4;

__device__ __forceinline__ short bfbits(float f) {
    __hip_bfloat16 h = __float2bfloat16(f);
    return *reinterpret_cast<short*>(&h);
}
__device__ __forceinline__ short8 cvt8(float4 a, float4 b) {
    short8 r;
    r[0] = bfbits(a.x); r[1] = bfbits(a.y); r[2] = bfbits(a.z); r[3] = bfbits(a.w);
    r[4] = bfbits(b.x); r[5] = bfbits(b.y); r[6] = bfbits(b.z); r[7] = bfbits(b.w);
    return r;
}
// XOR-swizzle for [rows][128B] bf16 LDS tiles (R9 probe: 0 bank conflicts).
__device__ __forceinline__ int swz(int row, int cb) {
    return row * 128 + (cb ^ ((row & 7) << 4));
}

// ---------------- f32 -> bf16 pre-convert (hid) ----------------
__global__ __launch_bounds__(256)
void f2b(const float* __restrict__ in, short* __restrict__ o) {
    int i = (blockIdx.x * 256 + threadIdx.x) * 8;
    float4 a = *(const float4*)(in + i);
    float4 b = *(const float4*)(in + i + 4);
    *(short8*)(o + i) = cvt8(a, b);
}

// ---------- bf16 MFMA GEMM: C[256][N] = A[256][K](bf16) * W[N][K]^T(f32) ----------
// BM=256 (W panel read once across the whole launch). TH=512: BN=64, 8 waves
// (4m x 2n); TH=256: BN=32, 4 waves. BK=64, dbuf LDS, 1 barrier/K-step.
// grid=(N/BN, 1, ksplit): block z covers k in [z*kc, (z+1)*kc), partial to
// C + z*256*ldc. (R9 counters: grid 133 -> 12.6% occupancy was THE gemm1
// bottleneck; ksplit raises block count without re-reading W.)
template<int TH, int BN>
__global__ __launch_bounds__(TH, 2)
void gemm_mfma(const short* __restrict__ A, const float* __restrict__ W,
               float* __restrict__ C, int lda, int ldb, int ldc, int kc) {
    constexpr int WNC = BN / 32;
    constexpr int ASL = 2048 / TH;
    constexpr int BBYTES = BN * 128;
    const int bn0 = blockIdx.x * BN;
    const int k0  = blockIdx.z * kc;
    C += (size_t)blockIdx.z * 256 * ldc;
    const int t = threadIdx.x;
    const int lane = t & 63;
    const int w = t >> 6;
    const int wm = w / WNC, wn = w % WNC;
    const int fr = lane & 15, fg = lane >> 4;

    __shared__ __align__(16) char lds[2][32768 + BBYTES];

    const short* apb[ASL]; int ao[ASL];
    #pragma unroll
    for (int i = 0; i < ASL; ++i) {
        int s = t + TH * i, r = s >> 3, sl = s & 7;
        apb[i] = A + (size_t)r * lda + k0 + sl * 8;
        ao[i] = swz(r, sl * 16);
    }
    const int br = t >> 3, bsl = t & 7;
    const float* bp = W + (size_t)(bn0 + br) * ldb + k0 + bsl * 8;
    const int bo = 32768 + swz(br, bsl * 16);

    int aro[4], bro[2];
    #pragma unroll
    for (int m = 0; m < 4; ++m) aro[m] = swz(wm * 64 + m * 16 + fr, fg * 16);
    #pragma unroll
    for (int n = 0; n < 2; ++n) bro[n] = 32768 + swz(wn * 32 + n * 16 + fr, fg * 16);

    f32x4 acc[4][2] = {};
    short8 rab[ASL];
    float4 rb0, rb1;

    #define LOADT(kt) { const int ko = (kt) << 6;                                \
        _Pragma("unroll") for (int i = 0; i < ASL; ++i)                          \
            rab[i] = *(const short8*)(apb[i] + ko);                              \
        rb0 = *(const float4*)(bp + ko); rb1 = *(const float4*)(bp + ko + 4); }
    #define STAGET(buf) {                                                        \
        _Pragma("unroll") for (int i = 0; i < ASL; ++i)                          \
            *(short8*)(lds[buf] + ao[i]) = rab[i];                               \
        *(short8*)(lds[buf] + bo) = cvt8(rb0, rb1); }

    LOADT(0);
    STAGET(0);
    int cur = 0;
    const int nT = kc >> 6;
    for (int kt = 0; kt < nT; ++kt) {
        if (kt + 1 < nT) LOADT(kt + 1);
        __syncthreads();
        #pragma unroll
        for (int ks = 0; ks < 2; ++ks) {
            short8 af[4], bf[2];
            #pragma unroll
            for (int m = 0; m < 4; ++m) af[m] = *(short8*)(lds[cur] + (aro[m] ^ (ks << 6)));
            #pragma unroll
            for (int n = 0; n < 2; ++n) bf[n] = *(short8*)(lds[cur] + (bro[n] ^ (ks << 6)));
            #pragma unroll
            for (int m = 0; m < 4; ++m)
                #pragma unroll
                for (int n = 0; n < 2; ++n)
                    acc[m][n] = __builtin_amdgcn_mfma_f32_16x16x32_bf16(af[m], bf[n], acc[m][n], 0, 0, 0);
        }
        if (kt + 1 < nT) STAGET(cur ^ 1);
        cur ^= 1;
    }
    #pragma unroll
    for (int m = 0; m < 4; ++m)
        #pragma unroll
        for (int n = 0; n < 2; ++n) {
            const int row = wm * 64 + m * 16 + fg * 4;
            const int col = bn0 + wn * 32 + n * 16 + fr;
            #pragma unroll
            for (int j = 0; j < 4; ++j)
                C[(size_t)(row + j) * ldc + col] = acc[m][n][j];
        }
    #undef LOADT
    #undef STAGET
}

// sum 4 split-K partials (gemm2)
__global__ __launch_bounds__(256)
void reduce4(const float* __restrict__ part, float* __restrict__ out) {
    const int i = (blockIdx.x * 256 + threadIdx.x) * 4;
    float4 s = *(const float4*)(part + i);
    #pragma unroll
    for (int k = 1; k < 4; ++k) {
        float4 p = *(const float4*)(part + (size_t)k * BATCH * DMODEL + i);
        s.x += p.x; s.y += p.y; s.z += p.z; s.w += p.w;
    }
    *(float4*)(out + i) = s;
}

// ---------- fused middle: conv+silu -> scalars -> SSM -> gate+RMSNorm ----------
// One block per batch element (256 x 1024 thr). Consumes gemm1's TWO split-K
// partials inline (zp0/zp1, zp = zp0 + zp1) -- no reduce kernel for gemm1.
// ssm loads are non-temporal: 512 MB single-use stream, keep L2 for weights.
__global__ __launch_bounds__(1024)
void fused_mid(const float* __restrict__ zp0, const float* __restrict__ zp1,
               const float* __restrict__ conv_state,
               const float* __restrict__ conv_w, const float* __restrict__ conv_b,
               const float* __restrict__ dt_bias, const float* __restrict__ A_log,
               const float* __restrict__ ssm, const float* __restrict__ Dp,
               const float* __restrict__ nw, short* __restrict__ yn) {
    const int b = blockIdx.x, t = threadIdx.x;
    const int lane = t & 63, w = t >> 6;            // 16 waves
    __shared__ float sxbc[CONVDIM];
    __shared__ float sy[DINNER];
    __shared__ float sred[16];
    __shared__ float sdA[NHEADS_], scoef[NHEADS_];

    // ---- phase 1: conv + silu (zx = zp0 + zp1) ----
    #pragma unroll
    for (int it = 0; it < 5; ++it) {
        int c = it * 1024 + t;
        if (c < CONVDIM) {
            float4 cs = *(const float4*)&conv_state[((size_t)b * CONVDIM + c) * 4];
            float4 w4 = *(const float4*)&conv_w[c * 4];
            float xin = zp0[(size_t)b * DINPROJ + DINNER + c]
                      + zp1[(size_t)b * DINPROJ + DINNER + c];
            float v = cs.y * w4.x + cs.z * w4.y + cs.w * w4.z + xin * w4.w + conv_b[c];
            sxbc[c] = v / (1.f + expf(-v));
        }
    }
    __syncthreads();

    // ---- phase 2: BC = B.C ; per-head dt, dA, coef ----
    if (t < 128) {
        float prod = sxbc[DINNER + t] * sxbc[DINNER + DSTATE + t];
        #pragma unroll
        for (int m = 1; m < 64; m <<= 1) prod += __shfl_xor(prod, m);
        if ((t & 63) == 0) sred[t >> 6] = prod;
    }
    __syncthreads();
    if (t < NHEADS_) {
        float BC = sred[0] + sred[1];
        float x = zp0[(size_t)b * DINPROJ + DINNER + CONVDIM + t]
                + zp1[(size_t)b * DINPROJ + DINNER + CONVDIM + t] + dt_bias[t];
        float dt = (x > 20.f) ? x : log1pf(expf(x));
        sdA[t] = expf(dt * (-expf(A_log[t])));
        scoef[t] = dt * BC + Dp[t];
    }
    __syncthreads();

    // ---- phase 3: SSM contraction (R5-verified pattern, nt loads via f32x4) ----
    {
        const int pq = lane >> 4, nl = lane & 15;
        const float4 c4a = *(const float4*)&sxbc[DINNER + DSTATE + nl * 8];
        const float4 c4b = *(const float4*)&sxbc[DINNER + DSTATE + nl * 8 + 4];
        #pragma unroll
        for (int k = 0; k < 4; ++k) {
            const int h = w * 4 + k;
            const float* S = ssm + (((size_t)b * NHEADS_ + h) * HEADDIM_) * DSTATE;
            const float dA = sdA[h], coef = scoef[h];
            #pragma unroll 8
            for (int pp = 0; pp < 16; ++pp) {
                const int p = pp * 4 + pq;
                f32x4 sa = __builtin_nontemporal_load((const f32x4*)&S[p * DSTATE + nl * 8]);
                f32x4 sb = __builtin_nontemporal_load((const f32x4*)&S[p * DSTATE + nl * 8 + 4]);
                float dot = sa[0] * c4a.x + sa[1] * c4a.y + sa[2] * c4a.z + sa[3] * c4a.w
                          + sb[0] * c4b.x + sb[1] * c4b.y + sb[2] * c4b.z + sb[3] * c4b.w;
                #pragma unroll
                for (int m = 1; m < 16; m <<= 1) dot += __shfl_xor(dot, m);
                if (nl == 0)
                    sy[h * HEADDIM_ + p] = dA * dot + sxbc[h * HEADDIM_ + p] * coef;
            }
        }
    }
    __syncthreads();

    // ---- phase 4: gate with silu(z = zp0+zp1), RMSNorm, -> bf16 ----
    {
        const int i = t * 4;
        float4 yv = *(const float4*)&sy[i];
        float4 z0 = *(const float4*)&zp0[(size_t)b * DINPROJ + i];
        float4 z1 = *(const float4*)&zp1[(size_t)b * DINPROJ + i];
        float4 zv = { z0.x + z1.x, z0.y + z1.y, z0.z + z1.z, z0.w + z1.w };
        float4 g;
        g.x = yv.x * (zv.x / (1.f + expf(-zv.x)));
        g.y = yv.y * (zv.y / (1.f + expf(-zv.y)));
        g.z = yv.z * (zv.z / (1.f + expf(-zv.z)));
        g.w = yv.w * (zv.w / (1.f + expf(-zv.w)));
        float ss = g.x * g.x + g.y * g.y + g.z * g.z + g.w * g.w;
        #pragma unroll
        for (int m = 1; m < 64; m <<= 1) ss += __shfl_xor(ss, m);
        __syncthreads();
        if (lane == 0) sred[w] = ss;
        __syncthreads();
        float tot = 0.f;
        #pragma unroll
        for (int k = 0; k < 16; ++k) tot += sred[k];
        const float sc = rsqrtf(tot * (1.f / DINNER) + EPS_);
        float4 w4 = *(const float4*)&nw[i];
        short4v o;
        o[0] = bfbits(g.x * sc * w4.x); o[1] = bfbits(g.y * sc * w4.y);
        o[2] = bfbits(g.z * sc * w4.z); o[3] = bfbits(g.w * sc * w4.w);
        *(short4v*)&yn[(size_t)b * DINNER + i] = o;
    }
}

extern "C" void kernel_launch(void* const* d_in, const int* in_sizes, int n_in,
                              void* d_out, int out_size, void* d_ws, size_t ws_size,
                              hipStream_t stream) {
    const float* hid        = (const float*)d_in[0];
    const float* conv_state = (const float*)d_in[1];
    const float* ssm        = (const float*)d_in[2];
    const float* W_in       = (const float*)d_in[3];
    const float* conv_w     = (const float*)d_in[4];
    const float* conv_b     = (const float*)d_in[5];
    const float* dt_bias    = (const float*)d_in[6];
    const float* A_log      = (const float*)d_in[7];
    const float* Dp         = (const float*)d_in[8];
    const float* norm_w     = (const float*)d_in[9];
    const float* W_out      = (const float*)d_in[10];
    float* out = (float*)d_out;

    float* ws    = (float*)d_ws;
    float* zpart = ws;                                   // 2 x 256*8512 f32 (gemm1 split-K partials)
    float* part  = zpart + (size_t)2 * BATCH * DINPROJ;  // 4 x 256*2048 f32 (gemm2 partials)
    short* hidbf = (short*)(part + (size_t)4 * BATCH * DMODEL);  // 256*2048 bf16
    short* yn_bf = hidbf + (size_t)BATCH * DMODEL;       // 256*4096 bf16

    // 0) hid -> bf16
    f2b<<<dim3(BATCH * DMODEL / 2048), 256, 0, stream>>>(hid, hidbf);
    // 1) zxbcdt = h @ W_in^T  (N=8512, K=2048): split-K x2 -> 266 blocks
    //    (R9: 133 blocks was 12.6% occupancy), W_in still read exactly once.
    gemm_mfma<512, 64><<<dim3(DINPROJ / 64, 1, 2), 512, 0, stream>>>(
        hidbf, W_in, zpart, DMODEL, DMODEL, DINPROJ, DMODEL / 2);
    // 2) fused conv/scalars/SSM/gate-norm; sums the two gemm1 partials inline
    fused_mid<<<dim3(BATCH), 1024, 0, stream>>>(
        zpart, zpart + (size_t)BATCH * DINPROJ,
        conv_state, conv_w, conv_b, dt_bias, A_log, ssm, Dp, norm_w, yn_bf);
    // 3) out = yn @ W_out^T  (N=2048, K=4096): split-K x4 -> 256 balanced blocks
    gemm_mfma<256, 32><<<dim3(DMODEL / 32, 1, 4), 256, 0, stream>>>(
        yn_bf, W_out, part, DINNER, DINNER, DMODEL, DINNER / 4);
    reduce4<<<dim3(BATCH * DMODEL / 1024), 256, 0, stream>>>(part, out);
}